// Round 1
// baseline (674.023 us; speedup 1.0000x reference)
//
#include <hip/hip_runtime.h>
#include <hip/hip_bf16.h>
#include <stdint.h>

#define IN_DIM 8192
#define OUT_DIM 4096
#define NNZ 1638400
#define BATCH 4096

#define BM 128
#define BN 128
#define BK 32

typedef __bf16 bf16x8 __attribute__((ext_vector_type(8)));
typedef float f32x4 __attribute__((ext_vector_type(4)));

// ---- helpers ----------------------------------------------------------------

__device__ __forceinline__ unsigned short f2bf(float f) {
  union { float f; unsigned int u; } v; v.f = f;
  unsigned int u = v.u;
  // round-to-nearest-even
  unsigned int r = (u + 0x7FFFu + ((u >> 16) & 1u)) >> 16;
  return (unsigned short)r;
}

__device__ __forceinline__ void async16(const void* g, void* l) {
  __builtin_amdgcn_global_load_lds(
      (const __attribute__((address_space(1))) unsigned int*)g,
      (__attribute__((address_space(3))) unsigned int*)l,
      16, 0, 0);
}

// ---- kernel 1: scatter-add weights into W^T (fp32) --------------------------
// Transposed layout [OUT_DIM][IN_DIM] is free (scatter is random either way)
// and gives the GEMM a B^T row-major operand with contiguous K.

__global__ void scatter_kernel(const int* __restrict__ row_idx,
                               const int* __restrict__ col_idx,
                               const float* __restrict__ w,
                               float* __restrict__ Wt) {
  int i = blockIdx.x * 256 + threadIdx.x;
  if (i < NNZ) {
    int r = row_idx[i];
    int c = col_idx[i];
    atomicAdd(Wt + (size_t)c * IN_DIM + r, w[i]);
  }
}

// ---- kernel 2: fp32 -> bf16 (RN), 8 elems/thread, 16B stores ----------------

__global__ void convert_kernel(const float* __restrict__ src,
                               unsigned short* __restrict__ dst) {
  int i = blockIdx.x * 256 + threadIdx.x;  // one thread per 8 elements
  const float4* s = (const float4*)src;
  float4 a = s[2 * i];
  float4 b = s[2 * i + 1];
  union { unsigned short us[8]; uint4 v; } o;
  o.us[0] = f2bf(a.x); o.us[1] = f2bf(a.y); o.us[2] = f2bf(a.z); o.us[3] = f2bf(a.w);
  o.us[4] = f2bf(b.x); o.us[5] = f2bf(b.y); o.us[6] = f2bf(b.z); o.us[7] = f2bf(b.w);
  ((uint4*)dst)[i] = o.v;
}

// ---- kernel 3: bf16 GEMM, m97 structure -------------------------------------
// C[M,N] = A[M,K] * Bt[N,K]^T + bias, M=BATCH, N=OUT_DIM, K=IN_DIM.
// 128x128 block tile, BK=32, 4 waves (2x2), each wave 64x64 via 4x4 frags of
// v_mfma_f32_16x16x32_bf16. Staging via global_load_lds width=16 (LDS layout
// contiguous in staging order -- no padding, per the wave-uniform-base rule).

__global__ __launch_bounds__(256) void gemm_kernel(
    const unsigned short* __restrict__ A,   // [BATCH][IN_DIM] bf16 bits
    const unsigned short* __restrict__ Bt,  // [OUT_DIM][IN_DIM] bf16 bits
    const float* __restrict__ bias,         // [OUT_DIM]
    float* __restrict__ C) {                // [BATCH][OUT_DIM]
  __shared__ alignas(16) unsigned short lA[BM * BK];  // 8 KiB
  __shared__ alignas(16) unsigned short lB[BN * BK];  // 8 KiB

  const int tid = threadIdx.x;
  const int m0 = blockIdx.y * BM;
  const int n0 = blockIdx.x * BN;

  const int wid = tid >> 6;
  const int lane = tid & 63;
  const int wm = wid >> 1;      // wave row (0..1)
  const int wn = wid & 1;       // wave col (0..1)
  const int quad = lane >> 4;   // 0..3
  const int lm = lane & 15;     // 0..15

  f32x4 acc[4][4] = {};

  // Precompute staging indices: t2 in {tid, tid+256}; r = t2>>2, cseg=(t2&3)*8
  const int r0 = tid >> 2;
  const int cs = (tid & 3) * 8;

  for (int kt = 0; kt < IN_DIM / BK; ++kt) {
    const int k0 = kt * BK;
    // stage A tile: rows m0..m0+127, cols k0..k0+31 -> lA row-major [128][32]
    async16(A + (m0 + r0) * IN_DIM + k0 + cs, (char*)lA + tid * 16);
    async16(A + (m0 + r0 + 64) * IN_DIM + k0 + cs, (char*)lA + (tid + 256) * 16);
    // stage B tile: rows n0..n0+127 of Bt
    async16(Bt + (n0 + r0) * IN_DIM + k0 + cs, (char*)lB + tid * 16);
    async16(Bt + (n0 + r0 + 64) * IN_DIM + k0 + cs, (char*)lB + (tid + 256) * 16);

    __syncthreads();

    bf16x8 af[4], bf[4];
#pragma unroll
    for (int i = 0; i < 4; ++i)
      af[i] = *(const bf16x8*)(lA + (wm * 64 + i * 16 + lm) * BK + quad * 8);
#pragma unroll
    for (int j = 0; j < 4; ++j)
      bf[j] = *(const bf16x8*)(lB + (wn * 64 + j * 16 + lm) * BK + quad * 8);

#pragma unroll
    for (int i = 0; i < 4; ++i)
#pragma unroll
      for (int j = 0; j < 4; ++j)
        acc[i][j] = __builtin_amdgcn_mfma_f32_16x16x32_bf16(af[i], bf[j], acc[i][j], 0, 0, 0);

    __syncthreads();
  }

  // Epilogue: C/D layout col = lane&15, row = quad*4 + reg  [m89-verified]
  const int ccol0 = n0 + wn * 64 + lm;
  const int crow0 = m0 + wm * 64;
#pragma unroll
  for (int j = 0; j < 4; ++j) {
    const int col = ccol0 + j * 16;
    const float bv = bias[col];
#pragma unroll
    for (int i = 0; i < 4; ++i) {
#pragma unroll
      for (int v = 0; v < 4; ++v) {
        const int row = crow0 + i * 16 + quad * 4 + v;
        C[(size_t)row * OUT_DIM + col] = acc[i][j][v] + bv;
      }
    }
  }
}

// ---- launch -----------------------------------------------------------------

extern "C" void kernel_launch(void* const* d_in, const int* in_sizes, int n_in,
                              void* d_out, int out_size, void* d_ws, size_t ws_size,
                              hipStream_t stream) {
  const float* x = (const float*)d_in[0];       // [4096][8192]
  const int* row_idx = (const int*)d_in[1];     // [NNZ]
  const int* col_idx = (const int*)d_in[2];     // [NNZ]
  const float* weights = (const float*)d_in[3]; // [NNZ]
  const float* bias = (const float*)d_in[4];    // [4096]
  float* out = (float*)d_out;                   // [4096][4096]

  const size_t W_F32_BYTES = (size_t)IN_DIM * OUT_DIM * 4;        // 128 MiB
  const size_t W_BF16_BYTES = (size_t)IN_DIM * OUT_DIM * 2;       // 64 MiB
  const size_t NEEDED = W_F32_BYTES + W_BF16_BYTES;               // 192 MiB
  if (ws_size < NEEDED) return;  // cannot run; fail loudly via wrong output

  float* Wt_f32 = (float*)d_ws;                                   // [0,128M)
  unsigned short* Wt_bf16 = (unsigned short*)((char*)d_ws + W_F32_BYTES);  // [128M,192M)
  unsigned short* x_bf16 = (unsigned short*)d_ws;  // reuses dead Wt_f32 [0,64M)

  // 1. zero W^T fp32 (ws is poisoned 0xAA before every call)
  hipMemsetAsync(Wt_f32, 0, W_F32_BYTES, stream);

  // 2. scatter-add (duplicates accumulate)
  scatter_kernel<<<(NNZ + 255) / 256, 256, 0, stream>>>(row_idx, col_idx, weights, Wt_f32);

  // 3. W^T fp32 -> bf16
  const int n8 = (IN_DIM * OUT_DIM) / 8;  // 4194304
  convert_kernel<<<n8 / 256, 256, 0, stream>>>(Wt_f32, Wt_bf16);

  // 4. x fp32 -> bf16 (overwrites Wt_f32 region only after step 3 has read it)
  convert_kernel<<<n8 / 256, 256, 0, stream>>>(x, x_bf16);

  // 5. GEMM + bias
  dim3 grid(OUT_DIM / BN, BATCH / BM);
  gemm_kernel<<<grid, 256, 0, stream>>>(x_bf16, Wt_bf16, bias, out);
}